// Round 8
// baseline (612.368 us; speedup 1.0000x reference)
//
#include <hip/hip_runtime.h>
#include <stdint.h>

#define BB 4
#define SS 2048
#define DMODEL 1024
#define NH 16
#define FF 4096
#define MROWS (BB*SS)   // 8192

typedef __bf16 bf16x8 __attribute__((ext_vector_type(8)));
typedef __bf16 bf16x2t __attribute__((ext_vector_type(2)));
typedef float f32x4 __attribute__((ext_vector_type(4)));
typedef float f32x16 __attribute__((ext_vector_type(16)));
typedef unsigned uintx4 __attribute__((ext_vector_type(4)));

__device__ __forceinline__ unsigned short f2b(float f) {
  unsigned u = __float_as_uint(f);
  unsigned r = (u + 0x7FFFu + ((u >> 16) & 1u)) >> 16;
  return (unsigned short)r;
}

__device__ __forceinline__ unsigned pack2bf(float a, float b) {
  bf16x2t v = {(__bf16)a, (__bf16)b};
  return __builtin_bit_cast(unsigned, v);
}

__device__ __forceinline__ void pls32(unsigned& x, unsigned& y) {
#if defined(__has_builtin) && __has_builtin(__builtin_amdgcn_permlane32_swap)
  auto r = __builtin_amdgcn_permlane32_swap(x, y, 0, 0);
  x = (unsigned)r[0];
  y = (unsigned)r[1];
#else
  const unsigned sx = (unsigned)__shfl_xor((int)x, 32, 64);
  const unsigned sy = (unsigned)__shfl_xor((int)y, 32, 64);
  const bool hi = ((threadIdx.x >> 5) & 1) != 0;
  const unsigned nx = hi ? sy : x;
  const unsigned ny = hi ? y : sx;
  x = nx; y = ny;
#endif
}

// async global->LDS, 16B per lane; LDS dest = wave-uniform base + lane*16
__device__ __forceinline__ void gload_lds16(const void* g, void* l) {
  __builtin_amdgcn_global_load_lds(
      (const __attribute__((address_space(1))) void*)g,
      (__attribute__((address_space(3))) void*)l, 16, 0, 0);
}

// XOR-swizzled fragment read from a [rows][64] bf16 LDS tile (GEMM)
__device__ __forceinline__ bf16x8 lds_frag(const unsigned short* base, int row, int k) {
  unsigned off = (unsigned)((row * 128 + k * 2) ^ ((row & 7) << 4));
  return *reinterpret_cast<const bf16x8*>(reinterpret_cast<const char*>(base) + off);
}

// ---------------- converts ----------------
__global__ __launch_bounds__(256) void f32_to_bf16_k(const float* __restrict__ in,
                                                     unsigned short* __restrict__ out, int n8) {
  const int i = blockIdx.x * 256 + threadIdx.x;
  if (i >= n8) return;
  const float4* p = reinterpret_cast<const float4*>(in) + (size_t)i * 2;
  const float4 a = p[0], c = p[1];
  uint4 o;
  o.x = (unsigned)f2b(a.x) | ((unsigned)f2b(a.y) << 16);
  o.y = (unsigned)f2b(a.z) | ((unsigned)f2b(a.w) << 16);
  o.z = (unsigned)f2b(c.x) | ((unsigned)f2b(c.y) << 16);
  o.w = (unsigned)f2b(c.z) | ((unsigned)f2b(c.w) << 16);
  reinterpret_cast<uint4*>(out)[i] = o;
}

__global__ __launch_bounds__(256) void transpose_convert_k(const float* __restrict__ in,
                                                           unsigned short* __restrict__ out,
                                                           int R, int C) {
  __shared__ float tile[32][33];
  const int c0 = blockIdx.x * 32, r0 = blockIdx.y * 32;
  const int tx = threadIdx.x, ty = threadIdx.y;
  #pragma unroll
  for (int i = 0; i < 4; ++i)
    tile[ty + i * 8][tx] = in[(size_t)(r0 + ty + i * 8) * C + c0 + tx];
  __syncthreads();
  #pragma unroll
  for (int i = 0; i < 4; ++i)
    out[(size_t)(c0 + ty + i * 8) * R + r0 + tx] = f2b(tile[tx][ty + i * 8]);
}

__global__ __launch_bounds__(256) void v_transpose_k(const unsigned short* __restrict__ Vb,
                                                     unsigned short* __restrict__ Vt) {
  __shared__ unsigned short tile[32][33];
  const int bh = blockIdx.z, b = bh >> 4, h = bh & 15;
  const int s0 = blockIdx.x * 32, d0 = blockIdx.y * 32;
  const int tx = threadIdx.x, ty = threadIdx.y;
  #pragma unroll
  for (int i = 0; i < 4; ++i)
    tile[ty + i * 8][tx] = Vb[(size_t)(b * SS + s0 + ty + i * 8) * DMODEL + h * 64 + d0 + tx];
  __syncthreads();
  #pragma unroll
  for (int i = 0; i < 4; ++i)
    Vt[(size_t)(bh * 64 + d0 + ty + i * 8) * SS + s0 + tx] = tile[tx][ty + i * 8];
}

__global__ __launch_bounds__(256) void mask_pack_k(const unsigned char* __restrict__ mask,
                                                   unsigned long long* __restrict__ mbits, int total) {
  const int idx = blockIdx.x * 256 + threadIdx.x;
  if (idx >= total) return;
  const uint4* p = reinterpret_cast<const uint4*>(mask) + (size_t)idx * 4;
  unsigned long long bits = 0ull;
  #pragma unroll
  for (int q = 0; q < 4; ++q) {
    uint4 v = p[q];
    unsigned wds[4] = {v.x, v.y, v.z, v.w};
    #pragma unroll
    for (int j = 0; j < 4; ++j)
      #pragma unroll
      for (int by = 0; by < 4; ++by)
        if ((wds[j] >> (by * 8)) & 0xFFu) bits |= 1ull << (q * 16 + j * 4 + by);
  }
  mbits[idx] = bits;
}

// ---------------- GEMM (round-4 gemm2): 128x128, counted-vmcnt 2-stage ----------------
// EPI: 1 = relu->bf16 out, 2 = f32 out, 3 = QKV split bf16 (Q pre-scaled by CQ)
#define CQ 0.18033688011112042f   // log2(e)/8
template <int EPI>
__global__ __launch_bounds__(256, 2) void gemm2_k(const unsigned short* __restrict__ A,
                                                  const unsigned short* __restrict__ Bt,
                                                  const float* __restrict__ bias_a,
                                                  const float* __restrict__ bias_b,
                                                  const float* __restrict__ bias_c,
                                                  void* __restrict__ Cout, int N, int K) {
  __shared__ __align__(16) unsigned short As[2][128 * 64];
  __shared__ __align__(16) unsigned short Bs[2][128 * 64];
  const int t = threadIdx.x;
  const int lane = t & 63, w = t >> 6;
  const int wr = w >> 1, wc = w & 1;
  const int lr = lane & 15, lg = lane >> 4;

  // bijective XCD swizzle + decode (M/128 = 64 always)
  const int nwg = gridDim.x;
  const int q8 = nwg >> 3;
  const int wg = (blockIdx.x & 7) * q8 + (blockIdx.x >> 3);
  const int mb = wg & 63, nb = wg >> 6;
  const int m0 = mb * 128, n0 = nb * 128;

  const int srow = t >> 3;
  const unsigned cxor = (unsigned)(((t & 7) * 16) ^ (((t >> 3) & 7) << 4));
  const char* Asrc = reinterpret_cast<const char*>(A) + ((size_t)(m0 + srow) * K) * 2 + cxor;
  const char* Bsrc = reinterpret_cast<const char*>(Bt) + ((size_t)(n0 + srow) * K) * 2 + cxor;
  const size_t rstep = (size_t)32 * K * 2;
  char* AsB[2] = {reinterpret_cast<char*>(As[0]) + w * 1024, reinterpret_cast<char*>(As[1]) + w * 1024};
  char* BsB[2] = {reinterpret_cast<char*>(Bs[0]) + w * 1024, reinterpret_cast<char*>(Bs[1]) + w * 1024};

  auto stage = [&](int buf, int kt) {
    const char* ak = Asrc + (size_t)kt * 128;
    const char* bk = Bsrc + (size_t)kt * 128;
    #pragma unroll
    for (int c = 0; c < 4; ++c) {
      gload_lds16(ak + c * rstep, AsB[buf] + c * 4096);
      gload_lds16(bk + c * rstep, BsB[buf] + c * 4096);
    }
  };

  f32x4 acc[4][4] = {};
  const int nt = K >> 6;

  stage(0, 0);
  stage(1, 1);
  asm volatile("s_waitcnt vmcnt(8)" ::: "memory");
  __builtin_amdgcn_s_barrier();

  int cur = 0;
  for (int kt = 0; kt < nt; ++kt) {
    bf16x8 af[2][4], bfr[2][4];
    #pragma unroll
    for (int kk = 0; kk < 2; ++kk) {
      #pragma unroll
      for (int m = 0; m < 4; ++m)
        af[kk][m] = lds_frag(As[cur], wr * 64 + m * 16 + lr, kk * 32 + lg * 8);
      #pragma unroll
      for (int n = 0; n < 4; ++n)
        bfr[kk][n] = lds_frag(Bs[cur], wc * 64 + n * 16 + lr, kk * 32 + lg * 8);
    }
    __builtin_amdgcn_s_setprio(1);
    #pragma unroll
    for (int m = 0; m < 4; ++m)
      #pragma unroll
      for (int n = 0; n < 4; ++n)
        acc[m][n] = __builtin_amdgcn_mfma_f32_16x16x32_bf16(af[0][m], bfr[0][n], acc[m][n], 0, 0, 0);
    __builtin_amdgcn_s_setprio(0);

    asm volatile("s_waitcnt lgkmcnt(0)" ::: "memory");
    __builtin_amdgcn_s_barrier();
    if (kt + 2 < nt) {
      stage(cur, kt + 2);
      asm volatile("s_waitcnt vmcnt(8)" ::: "memory");
    } else {
      asm volatile("s_waitcnt vmcnt(0)" ::: "memory");
    }
    __builtin_amdgcn_s_barrier();
    __builtin_amdgcn_sched_barrier(0);

    __builtin_amdgcn_s_setprio(1);
    #pragma unroll
    for (int m = 0; m < 4; ++m)
      #pragma unroll
      for (int n = 0; n < 4; ++n)
        acc[m][n] = __builtin_amdgcn_mfma_f32_16x16x32_bf16(af[1][m], bfr[1][n], acc[m][n], 0, 0, 0);
    __builtin_amdgcn_s_setprio(0);
    cur ^= 1;
  }

  const int ccol0 = wc * 64;
  if constexpr (EPI == 3) {
    const int g3 = n0 >> 10;  // 0=Q,1=K,2=V
    const float* bias = (g3 == 0) ? bias_a : (g3 == 1) ? bias_b : bias_c;
    const float scl = (g3 == 0) ? CQ : 1.0f;
    unsigned short* Og = reinterpret_cast<unsigned short*>(Cout) + (size_t)g3 * MROWS * DMODEL;
    const int ncol0 = (n0 & 1023) + ccol0;
    float bv[4];
    #pragma unroll
    for (int n = 0; n < 4; ++n) bv[n] = bias[ncol0 + n * 16 + lr];
    #pragma unroll
    for (int m = 0; m < 4; ++m)
      #pragma unroll
      for (int n = 0; n < 4; ++n)
        #pragma unroll
        for (int i = 0; i < 4; ++i) {
          const float v = (acc[m][n][i] + bv[n]) * scl;
          const size_t row = (size_t)(m0 + wr * 64 + m * 16 + lg * 4 + i);
          Og[row * DMODEL + (ncol0 + n * 16 + lr)] = f2b(v);
        }
  } else {
    float bv[4];
    #pragma unroll
    for (int n = 0; n < 4; ++n) bv[n] = bias_a[n0 + ccol0 + n * 16 + lr];
    #pragma unroll
    for (int m = 0; m < 4; ++m)
      #pragma unroll
      for (int n = 0; n < 4; ++n)
        #pragma unroll
        for (int i = 0; i < 4; ++i) {
          float v = acc[m][n][i] + bv[n];
          if (EPI == 1) v = fmaxf(v, 0.0f);
          const size_t row = (size_t)(m0 + wr * 64 + m * 16 + lg * 4 + i);
          const size_t col = (size_t)(n0 + ccol0 + n * 16 + lr);
          if (EPI == 2) reinterpret_cast<float*>(Cout)[row * N + col] = v;
          else          reinterpret_cast<unsigned short*>(Cout)[row * N + col] = f2b(v);
        }
  }
}

// ---------------- flash attention v5: direct-global fragments, ZERO barriers ----------------
// 4 independent waves x 32 q-rows = 128 q/block. A-operands (K rows, Vt rows) are
// per-lane 16B global loads from the L2-resident head (512KB); no LDS staging, no
// __syncthreads, no vmcnt in the loop. Q pre-scaled by log2(e)/8; mask fill -20.
__global__ __launch_bounds__(256) void attn5_k(const unsigned short* __restrict__ Qb,
                                               const unsigned short* __restrict__ Kb,
                                               const unsigned short* __restrict__ Vt,
                                               const unsigned long long* __restrict__ mbits,
                                               unsigned short* __restrict__ ctx) {
  __shared__ __align__(16) unsigned short Obs[4][2048];   // per-warp epilogue scratch

  const int t = threadIdx.x;
  const int lane = t & 63, w = t >> 6;
  const int lo = lane & 31, hi = lane >> 5;

  const int flat = blockIdx.x;
  const int bid = (flat & 7) * 128 + (flat >> 3);   // bijective XCD swizzle (1024 wg)
  const int bh = bid >> 4, qb = bid & 15;
  const int b = bh >> 4, h = bh & 15;
  const int q0 = qb * 128 + w * 32;

  bf16x8 qf[4];
  {
    const unsigned short* qp = Qb + (size_t)(b * SS + q0 + lo) * DMODEL + h * 64 + hi * 8;
    #pragma unroll
    for (int ds = 0; ds < 4; ++ds) qf[ds] = *reinterpret_cast<const bf16x8*>(qp + ds * 16);
  }

  const unsigned short* Kh = Kb + (size_t)b * SS * DMODEL + h * 64;   // K rows, stride DMODEL
  const unsigned short* Vh = Vt + (size_t)bh * 64 * SS;               // Vt rows (d), stride SS
  const unsigned long long* mrow = mbits + (size_t)(b * SS + q0 + lo) * (SS / 64);

  f32x16 ao0 = {}, ao1 = {};
  float lrun = 0.0f;

  for (int kv = 0; kv < SS / 64; ++kv) {
    const int kv0 = kv * 64;
    const unsigned long long mb = mrow[kv];

    // S^T = K_tile * Q : A-frag rows lo / 32+lo straight from global
    const unsigned short* kp0 = Kh + (size_t)(kv0 + lo) * DMODEL + hi * 8;
    const unsigned short* kp1 = kp0 + (size_t)32 * DMODEL;
    f32x16 st0 = {}, st1 = {};
    #pragma unroll
    for (int ds = 0; ds < 4; ++ds) {
      const bf16x8 k0 = *reinterpret_cast<const bf16x8*>(kp0 + ds * 16);
      const bf16x8 k1 = *reinterpret_cast<const bf16x8*>(kp1 + ds * 16);
      st0 = __builtin_amdgcn_mfma_f32_32x32x16_bf16(k0, qf[ds], st0, 0, 0, 0);
      st1 = __builtin_amdgcn_mfma_f32_32x32x16_bf16(k1, qf[ds], st1, 0, 0, 0);
    }

    if (__any(mb != 0ull)) {
      #pragma unroll
      for (int r = 0; r < 16; ++r) {
        const int k = (r & 3) + 8 * (r >> 2) + 4 * hi;
        if ((mb >> k) & 1ull) st0[r] = -20.0f;
        if ((mb >> (k + 32)) & 1ull) st1[r] = -20.0f;
      }
    }

    // no-max softmax: p = exp2(st); tree-sum denominator
    float ps[16];
    #pragma unroll
    for (int r = 0; r < 16; ++r) {
      st0[r] = exp2f(st0[r]);
      st1[r] = exp2f(st1[r]);
      ps[r] = st0[r] + st1[r];
    }
    #pragma unroll
    for (int r = 0; r < 8; ++r) ps[r] += ps[r + 8];
    #pragma unroll
    for (int r = 0; r < 4; ++r) ps[r] += ps[r + 4];
    float ls = (ps[0] + ps[1]) + (ps[2] + ps[3]);
    ls += __shfl_xor(ls, 32, 64);
    lrun += ls;

    // P -> bf16 B-fragments via pack + permlane32_swap (T12)
    unsigned pw[16];
    #define PACK8(SV, KB)                                            \
      {                                                              \
        unsigned c0 = pack2bf(SV[0], SV[1]);                         \
        unsigned c1 = pack2bf(SV[2], SV[3]);                         \
        unsigned c2 = pack2bf(SV[4], SV[5]);                         \
        unsigned c3 = pack2bf(SV[6], SV[7]);                         \
        unsigned c4 = pack2bf(SV[8], SV[9]);                         \
        unsigned c5 = pack2bf(SV[10], SV[11]);                       \
        unsigned c6 = pack2bf(SV[12], SV[13]);                       \
        unsigned c7 = pack2bf(SV[14], SV[15]);                       \
        pls32(c0, c2); pls32(c1, c3); pls32(c4, c6); pls32(c5, c7);  \
        pw[(KB) + 0] = c0; pw[(KB) + 1] = c1;                        \
        pw[(KB) + 2] = c2; pw[(KB) + 3] = c3;                        \
        pw[(KB) + 4] = c4; pw[(KB) + 5] = c5;                        \
        pw[(KB) + 6] = c6; pw[(KB) + 7] = c7;                        \
      }
    PACK8(st0, 0)
    PACK8(st1, 8)
    #undef PACK8

    // O^T += V^T * P^T : A-frag rows (d = lo / 32+lo) straight from global
    const unsigned short* vp0 = Vh + (size_t)lo * SS + kv0 + hi * 8;
    const unsigned short* vp1 = vp0 + (size_t)32 * SS;
    #pragma unroll
    for (int ks = 0; ks < 4; ++ks) {
      const uintx4 pv = {pw[ks * 4 + 0], pw[ks * 4 + 1], pw[ks * 4 + 2], pw[ks * 4 + 3]};
      const bf16x8 pb = __builtin_bit_cast(bf16x8, pv);
      const bf16x8 v0 = *reinterpret_cast<const bf16x8*>(vp0 + ks * 16);
      const bf16x8 v1 = *reinterpret_cast<const bf16x8*>(vp1 + ks * 16);
      ao0 = __builtin_amdgcn_mfma_f32_32x32x16_bf16(v0, pb, ao0, 0, 0, 0);
      ao1 = __builtin_amdgcn_mfma_f32_32x32x16_bf16(v1, pb, ao1, 0, 0, 0);
    }
  }

  // epilogue: normalize, transpose via wave-private LDS region (no barriers needed)
  const float inv = 1.0f / lrun;
  unsigned short* Ob = &Obs[w][0];
  #pragma unroll
  for (int dt = 0; dt < 2; ++dt) {
    #pragma unroll
    for (int r = 0; r < 16; ++r) {
      const int d = dt * 32 + (r & 3) + 8 * (r >> 2) + 4 * hi;
      const float v = (dt ? ao1[r] : ao0[r]) * inv;
      const unsigned off = (unsigned)((lo * 128 + d * 2) ^ ((lo & 7) << 4));
      *reinterpret_cast<unsigned short*>(reinterpret_cast<char*>(Ob) + off) = f2b(v);
    }
  }
  const int rr = lane >> 1, xh = (lane & 1) * 64;
  char* crow_g = reinterpret_cast<char*>(ctx) +
                 ((size_t)(b * SS + q0 + rr) * DMODEL + h * 64) * 2;
  #pragma unroll
  for (int c = 0; c < 4; ++c) {
    const unsigned off = (unsigned)((rr * 128 + xh + c * 16) ^ ((rr & 7) << 4));
    const uint4 vv = *reinterpret_cast<const uint4*>(reinterpret_cast<const char*>(Ob) + off);
    *reinterpret_cast<uint4*>(crow_g + xh + c * 16) = vv;
  }
}

// ---------------- LayerNorm(a + res) ----------------
__global__ __launch_bounds__(256) void ln_k(const float* __restrict__ a,
                                            const float* __restrict__ res,
                                            const float* __restrict__ g,
                                            const float* __restrict__ be,
                                            float* __restrict__ of,
                                            unsigned short* __restrict__ ob) {
  const int row = blockIdx.x, t = threadIdx.x;
  float4 v = reinterpret_cast<const float4*>(a + (size_t)row * DMODEL)[t];
  const float4 r = reinterpret_cast<const float4*>(res + (size_t)row * DMODEL)[t];
  v.x += r.x; v.y += r.y; v.z += r.z; v.w += r.w;
  float s = v.x + v.y + v.z + v.w;
  float ss = v.x * v.x + v.y * v.y + v.z * v.z + v.w * v.w;
  #pragma unroll
  for (int off = 1; off < 64; off <<= 1) {
    s += __shfl_xor(s, off, 64);
    ss += __shfl_xor(ss, off, 64);
  }
  __shared__ float red[8];
  const int wv = t >> 6;
  if ((t & 63) == 0) { red[wv] = s; red[4 + wv] = ss; }
  __syncthreads();
  s = red[0] + red[1] + red[2] + red[3];
  ss = red[4] + red[5] + red[6] + red[7];
  const float mu = s * (1.0f / DMODEL);
  const float rs = rsqrtf(ss * (1.0f / DMODEL) - mu * mu + 1e-6f);
  const float4 gg = reinterpret_cast<const float4*>(g)[t];
  const float4 bb = reinterpret_cast<const float4*>(be)[t];
  float4 o;
  o.x = (v.x - mu) * rs * gg.x + bb.x;
  o.y = (v.y - mu) * rs * gg.y + bb.y;
  o.z = (v.z - mu) * rs * gg.z + bb.z;
  o.w = (v.w - mu) * rs * gg.w + bb.w;
  if (of) reinterpret_cast<float4*>(of + (size_t)row * DMODEL)[t] = o;
  if (ob) {
    ushort4 u;
    u.x = f2b(o.x); u.y = f2b(o.y); u.z = f2b(o.z); u.w = f2b(o.w);
    reinterpret_cast<ushort4*>(ob + (size_t)row * DMODEL)[t] = u;
  }
}

extern "C" void kernel_launch(void* const* d_in, const int* in_sizes, int n_in,
                              void* d_out, int out_size, void* d_ws, size_t ws_size,
                              hipStream_t stream) {
  const float* src = (const float*)d_in[0];
  const unsigned char* mask = (const unsigned char*)d_in[1];
  const float* Wq = (const float*)d_in[2];
  const float* bq = (const float*)d_in[3];
  const float* Wk = (const float*)d_in[4];
  const float* bk = (const float*)d_in[5];
  const float* Wv = (const float*)d_in[6];
  const float* bv = (const float*)d_in[7];
  const float* Wo = (const float*)d_in[8];
  const float* bo = (const float*)d_in[9];
  const float* ln1_g = (const float*)d_in[10];
  const float* ln1_b = (const float*)d_in[11];
  const float* W1 = (const float*)d_in[12];
  const float* b1 = (const float*)d_in[13];
  const float* W2 = (const float*)d_in[14];
  const float* b2 = (const float*)d_in[15];
  const float* ln2_g = (const float*)d_in[16];
  const float* ln2_b = (const float*)d_in[17];

  char* ws = (char*)d_ws;
  size_t off = 0;
  auto alloc = [&](size_t bytes) {
    char* p = ws + off;
    off += (bytes + 255) & ~(size_t)255;
    return p;
  };
  unsigned short* srcb = (unsigned short*)alloc((size_t)MROWS * DMODEL * 2);
  unsigned short* WqT  = (unsigned short*)alloc((size_t)DMODEL * DMODEL * 2);
  unsigned short* WkT  = (unsigned short*)alloc((size_t)DMODEL * DMODEL * 2);
  unsigned short* WvT  = (unsigned short*)alloc((size_t)DMODEL * DMODEL * 2);
  unsigned short* WoT  = (unsigned short*)alloc((size_t)DMODEL * DMODEL * 2);
  unsigned short* W1T  = (unsigned short*)alloc((size_t)FF * DMODEL * 2);
  unsigned short* W2T  = (unsigned short*)alloc((size_t)DMODEL * FF * 2);
  unsigned short* Qb   = (unsigned short*)alloc((size_t)MROWS * DMODEL * 2);
  unsigned short* Kb   = (unsigned short*)alloc((size_t)MROWS * DMODEL * 2);
  unsigned short* Vb   = (unsigned short*)alloc((size_t)MROWS * DMODEL * 2);
  unsigned short* Vt   = (unsigned short*)alloc((size_t)MROWS * DMODEL * 2);
  unsigned short* ctx  = (unsigned short*)alloc((size_t)MROWS * DMODEL * 2);
  float*          xf   = (float*)alloc((size_t)MROWS * DMODEL * 4);
  unsigned short* xb   = (unsigned short*)alloc((size_t)MROWS * DMODEL * 2);
  unsigned short* hb   = (unsigned short*)alloc((size_t)MROWS * FF * 2);
  unsigned long long* mbits = (unsigned long long*)alloc((size_t)BB * SS * (SS / 64) * 8);
  float* outf = (float*)d_out;
  (void)Kb; (void)Vb;

  // converts
  f32_to_bf16_k<<<(MROWS * DMODEL / 8 + 255) / 256, 256, 0, stream>>>(src, srcb, MROWS * DMODEL / 8);
  dim3 tb(32, 8);
  transpose_convert_k<<<dim3(32, 32), tb, 0, stream>>>(Wq, WqT, DMODEL, DMODEL);
  transpose_convert_k<<<dim3(32, 32), tb, 0, stream>>>(Wk, WkT, DMODEL, DMODEL);
  transpose_convert_k<<<dim3(32, 32), tb, 0, stream>>>(Wv, WvT, DMODEL, DMODEL);
  transpose_convert_k<<<dim3(32, 32), tb, 0, stream>>>(Wo, WoT, DMODEL, DMODEL);
  transpose_convert_k<<<dim3(FF / 32, 32), tb, 0, stream>>>(W1, W1T, DMODEL, FF);
  transpose_convert_k<<<dim3(32, FF / 32), tb, 0, stream>>>(W2, W2T, FF, DMODEL);
  mask_pack_k<<<(BB * SS * (SS / 64) + 255) / 256, 256, 0, stream>>>(mask, mbits, BB * SS * (SS / 64));

  // fused QKV projection (N = 3072), 64 x 24 = 1536 blocks; Q pre-scaled by log2e/8
  gemm2_k<3><<<dim3(64 * 24), 256, 0, stream>>>(srcb, WqT, bq, bk, bv, Qb, 3072, DMODEL);

  v_transpose_k<<<dim3(SS / 32, 2, BB * NH), tb, 0, stream>>>(Vb, Vt);

  // barrier-free direct-global flash attention
  attn5_k<<<dim3((SS / 128) * BB * NH), 256, 0, stream>>>(Qb, Kb, Vt, mbits, ctx);

  // output projection -> d_out (f32 att_out), 64 x 8 = 512 blocks
  gemm2_k<2><<<dim3(64 * 8), 256, 0, stream>>>(ctx, WoT, bo, nullptr, nullptr, outf, DMODEL, DMODEL);

  // x = LN1(src + att_out) -> xf (f32) + xb (bf16)
  ln_k<<<MROWS, 256, 0, stream>>>(outf, src, ln1_g, ln1_b, xf, xb);

  // FFN: W1 (relu, 64 x 32 = 2048 blocks), W2 (64 x 8 = 512 blocks)
  gemm2_k<1><<<dim3(64 * 32), 256, 0, stream>>>(xb, W1T, b1, nullptr, nullptr, hb, FF, DMODEL);
  gemm2_k<2><<<dim3(64 * 8), 256, 0, stream>>>(hb, W2T, b2, nullptr, nullptr, outf, DMODEL, FF);

  // out = LN2(ffn_out + x) in-place on d_out
  ln_k<<<MROWS, 256, 0, stream>>>(outf, xf, ln2_g, ln2_b, outf, nullptr);
}